// Round 16
// baseline (93.418 us; speedup 1.0000x reference)
//
#include <hip/hip_runtime.h>

// B=4, N=4096, D=128 fixed by the reference setup.
// d_ws layout: [0, 4MiB) h as bf16 bits (ushort), [4MiB, +64KiB) sq fp32.

typedef float  f32x4   __attribute__((ext_vector_type(4)));
typedef float  f32x16  __attribute__((ext_vector_type(16)));
typedef short  bf16x8  __attribute__((ext_vector_type(8)));
typedef __attribute__((address_space(3))) void       lds_void_t;
typedef const __attribute__((address_space(1))) void gvoid_t;

__device__ inline float bf2f(unsigned int u) {
    union { unsigned int i; float f; } c; c.i = u << 16; return c.f;
}
__device__ inline unsigned short f2bf(float f) {
    union { float f; unsigned int i; } c; c.f = f;
    unsigned int r = c.i + 0x7fffu + ((c.i >> 16) & 1u);   // RNE
    return (unsigned short)(r >> 16);
}

// ---------------- Kernel A: h = bf16(x @ W^T + b), plus sq[row] = ||h_row||^2 ----
#define KA_ROWS 32
__global__ __launch_bounds__(256) void proj_kernel(
    const float* __restrict__ x, const float* __restrict__ W,
    const float* __restrict__ bias, unsigned short* __restrict__ h,
    float* __restrict__ sq)
{
    __shared__ __align__(16) unsigned short W5[32 * 4 * 32 * 4]; // 32 KiB
    __shared__ float xs[KA_ROWS][132];
    const int t = threadIdx.x;
    const long r0 = (long)blockIdx.x * KA_ROWS;

    for (int q = t; q < 4096; q += 256) {
        float4 w4 = ((const float4*)W)[q];
        int e = q >> 5, d4 = q & 31;
        int eb = e >> 2, ei = e & 3;
        ushort4 o;
        o.x = f2bf(w4.x); o.y = f2bf(w4.y); o.z = f2bf(w4.z); o.w = f2bf(w4.w);
        *(ushort4*)&W5[d4 * 256 + ei * 64 + ((eb ^ d4) & 31) * 4] = o;
    }
    const float4* xsrc = (const float4*)(x + r0 * 128);
    for (int q = t; q < KA_ROWS * 32; q += 256) {
        float4 v = xsrc[q];
        int r = q >> 5, d = (q & 31) << 2;
        xs[r][d] = v.x; xs[r][d + 1] = v.y; xs[r][d + 2] = v.z; xs[r][d + 3] = v.w;
    }
    __syncthreads();

    const int eb = t & 31, rb = t >> 5;
    const int e0 = eb * 4, rr0 = rb * 4;

    float acc_[4][4];
    #pragma unroll
    for (int ei = 0; ei < 4; ++ei) {
        float bv = bias[e0 + ei];
        #pragma unroll
        for (int ri = 0; ri < 4; ++ri) acc_[ri][ei] = bv;
    }

    for (int d4 = 0; d4 < 32; ++d4) {
        float wv[4][4];
        #pragma unroll
        for (int ei = 0; ei < 4; ++ei) {
            ushort4 u = *(const ushort4*)&W5[d4 * 256 + ei * 64 + ((eb ^ d4) & 31) * 4];
            wv[ei][0] = bf2f(u.x); wv[ei][1] = bf2f(u.y);
            wv[ei][2] = bf2f(u.z); wv[ei][3] = bf2f(u.w);
        }
        #pragma unroll
        for (int ri = 0; ri < 4; ++ri) {
            float4 xv = *(const float4*)&xs[rr0 + ri][d4 * 4];
            #pragma unroll
            for (int ei = 0; ei < 4; ++ei) {
                acc_[ri][ei] = fmaf(xv.x, wv[ei][0],
                               fmaf(xv.y, wv[ei][1],
                               fmaf(xv.z, wv[ei][2],
                               fmaf(xv.w, wv[ei][3], acc_[ri][ei]))));
            }
        }
    }

    float s[4] = {0.f, 0.f, 0.f, 0.f};
    #pragma unroll
    for (int ri = 0; ri < 4; ++ri) {
        ushort4 o;
        float v0 = bf2f(o.x = f2bf(acc_[ri][0]));
        float v1 = bf2f(o.y = f2bf(acc_[ri][1]));
        float v2 = bf2f(o.z = f2bf(acc_[ri][2]));
        float v3 = bf2f(o.w = f2bf(acc_[ri][3]));
        s[ri] = v0 * v0 + v1 * v1 + v2 * v2 + v3 * v3;
        *(ushort4*)&h[(r0 + rr0 + ri) * 128 + e0] = o;
    }
    #pragma unroll
    for (int ri = 0; ri < 4; ++ri) {
        #pragma unroll
        for (int m = 16; m > 0; m >>= 1) s[ri] += __shfl_xor(s[ri], m, 64);
    }
    if (eb == 0) {
        #pragma unroll
        for (int ri = 0; ri < 4; ++ri) sq[r0 + rr0 + ri] = s[ri];
    }
}

// ---------------- Kernel B: persistent pipelined gram, vmcnt-clean loop -------
// 256 blocks = 1/CU, ONE round. i-panel (256x128, 64 KiB) staged once;
// 1024-col j-range swept as 8 double-buffered 256x128 subtiles (2 x 32 KiB).
// ALL sq staged to LDS at prologue (R15's proven fix): after the prologue the
// loop issues ONLY {ds_read, MFMA, VALU/trans, nt stores, 4 staging loads}.
// Iter ends with s_waitcnt vmcnt(48) (staging loads are older than this
// subtile's 64 stores -> retired; <=48 stores stay in flight) + RAW s_barrier.
// Subtile k's store drain overlaps subtile k+1's compute. XCD affinity keeps
// all reads L2-resident.
__global__ __launch_bounds__(512, 2) void gram_kernel(
    const unsigned short* __restrict__ h, const float* __restrict__ sq,
    float* __restrict__ out)
{
    __shared__ __align__(16) unsigned short hsI[256 * 128];   // 64 KiB
    __shared__ __align__(16) unsigned short hsJ0[128 * 128];  // 32 KiB
    __shared__ __align__(16) unsigned short hsJ1[128 * 128];  // 32 KiB
    __shared__ float sqi_s[256];                              // 1 KiB
    __shared__ float sqj_s[1024];                             // 4 KiB
    const int bid = blockIdx.x;                       // 256 blocks
    const int xcd = bid & 7;
    const int bb  = xcd >> 1;                         // batch -> XCD pair
    const int tloc = ((bid >> 3) << 1) | (xcd & 1);   // 0..63 within batch
    const int it = tloc >> 2, jr = tloc & 3;
    const int i0l = it * 256;                         // batch-local i row base
    const int j0l = jr * 1024;                        // batch-local j col base
    const long ibase_g = (long)bb * 4096 + i0l;
    const long jrow_g  = (long)bb * 4096 + j0l;
    const int t = threadIdx.x, w = t >> 6, lane = t & 63;
    const int l31 = lane & 31, lh = lane >> 5;
    const int wr = w >> 1, wc = w & 1;                // wave -> 64(i) x 64(j)
    const char* hb = (const char*)h;

    #define STAGE_I()                                                          \
        { _Pragma("unroll")                                                    \
          for (int q = 0; q < 8; ++q) {                                        \
            int p = (q * 512 + t) << 4; int row = p >> 8;                      \
            int cs = ((p >> 4) & 15) ^ (row & 15);                             \
            __builtin_amdgcn_global_load_lds(                                  \
                (gvoid_t*)(hb + ((ibase_g + row) << 8) + (cs << 4)),           \
                (lds_void_t*)(((char*)hsI) + (unsigned)p), 16, 0, 0); } }

    #define STAGE_J(dst, jtn)                                                  \
        { _Pragma("unroll")                                                    \
          for (int q = 0; q < 4; ++q) {                                        \
            int p = (q * 512 + t) << 4; int row = p >> 8;                      \
            int cs = ((p >> 4) & 15) ^ (row & 15);                             \
            __builtin_amdgcn_global_load_lds(                                  \
                (gvoid_t*)(hb + ((jrow_g + (jtn) * 128 + row) << 8) + (cs << 4)), \
                (lds_void_t*)(((char*)(dst)) + (unsigned)p), 16, 0, 0); } }

    STAGE_I();
    STAGE_J(hsJ0, 0);
    // sq -> LDS: the ONLY global sq loads in the kernel
    if (t < 256) sqi_s[t] = sq[ibase_g + t];
    sqj_s[t]       = sq[jrow_g + t];
    sqj_s[t + 512] = sq[jrow_g + t + 512];

    float* ob = out + ((size_t)bb << 24) + ((size_t)i0l << 12) + j0l;
    const char* hI = (const char*)hsI;

    __syncthreads();   // prologue: no stores outstanding, full drain is fine

    // sq_i per acc reg -> registers (from LDS)
    float sqi_r[2][16];
    #pragma unroll
    for (int rb = 0; rb < 2; ++rb)
        #pragma unroll
        for (int reg = 0; reg < 16; ++reg)
            sqi_r[rb][reg] =
                sqi_s[wr * 64 + rb * 32 + (reg & 3) + 8 * (reg >> 2) + 4 * lh];

    for (int jt = 0; jt < 8; ++jt) {
        const char* hJ = (jt & 1) ? (const char*)hsJ1 : (const char*)hsJ0;

        f32x16 acc[2][2] = {};
        #pragma unroll
        for (int ks = 0; ks < 8; ++ks) {              // K = 8 x 16
            bf16x8 af[2], bg[2];
            #pragma unroll
            for (int rb = 0; rb < 2; ++rb) {
                int rowA = wr * 64 + rb * 32 + l31;
                int cA = ((ks * 2 + lh) ^ (rowA & 15)) << 4;
                af[rb] = *(const bf16x8*)(hI + (rowA << 8) + cA);
                int rowB = wc * 64 + rb * 32 + l31;
                int cB = ((ks * 2 + lh) ^ (rowB & 15)) << 4;
                bg[rb] = *(const bf16x8*)(hJ + (rowB << 8) + cB);
            }
            #pragma unroll
            for (int rb = 0; rb < 2; ++rb)
                #pragma unroll
                for (int nb = 0; nb < 2; ++nb)
                    acc[rb][nb] = __builtin_amdgcn_mfma_f32_32x32x16_bf16(
                        af[rb], bg[nb], acc[rb][nb], 0, 0, 0);
        }

        // prefetch next j-subtile BEFORE the stores (loads older than stores)
        if (jt < 7) { if (jt & 1) STAGE_J(hsJ0, jt + 1) else STAGE_J(hsJ1, jt + 1) }

        // epilogue: sq from LDS/regs only -> zero global loads between stores
        float sqj_n[2];
        #pragma unroll
        for (int nb = 0; nb < 2; ++nb)
            sqj_n[nb] = sqj_s[jt * 128 + wc * 64 + nb * 32 + l31];

        #pragma unroll
        for (int rb = 0; rb < 2; ++rb) {
            #pragma unroll
            for (int reg = 0; reg < 16; ++reg) {
                int il = wr * 64 + rb * 32 + (reg & 3) + 8 * (reg >> 2) + 4 * lh;
                int grow = i0l + il;
                #pragma unroll
                for (int nb = 0; nb < 2; ++nb) {
                    int jl = jt * 128 + wc * 64 + nb * 32 + l31;
                    float d2 = fmaxf(fmaf(acc[rb][nb][reg], -2.0f,
                                          sqi_r[rb][reg] + sqj_n[nb]), 0.0f);
                    float val = __expf(-__builtin_amdgcn_sqrtf(d2));
                    if (grow == j0l + jl) val = 1.0f;     // exact diagonal
                    __builtin_nontemporal_store(val, ob + ((long)il << 12) + jl);
                }
            }
        }

        if (jt < 7) {
            // staging loads (older than this subtile's 64 stores) retired once
            // outstanding <= 48; up to 48 stores remain in flight across the
            // RAW barrier and drain under the next subtile's compute.
            asm volatile("s_waitcnt vmcnt(48)" ::: "memory");
            __builtin_amdgcn_s_barrier();
        }
    }
    #undef STAGE_I
    #undef STAGE_J
}

extern "C" void kernel_launch(void* const* d_in, const int* in_sizes, int n_in,
                              void* d_out, int out_size, void* d_ws, size_t ws_size,
                              hipStream_t stream) {
    const float* x = (const float*)d_in[0];   // [4,4096,128]
    const float* W = (const float*)d_in[1];   // [128,128]
    const float* b = (const float*)d_in[2];   // [128]
    float* out = (float*)d_out;               // [4,4096,4096]

    unsigned short* h = (unsigned short*)d_ws;                       // 16384*128 bf16
    float* sq = (float*)((char*)d_ws + (size_t)16384 * 128 * 2);     // 16384 fp32

    proj_kernel<<<dim3(16384 / KA_ROWS), dim3(256), 0, stream>>>(x, W, b, h, sq);
    gram_kernel<<<dim3(256), dim3(512), 0, stream>>>(h, sq, out);
}

// Round 17
// 73.768 us; speedup vs baseline: 1.2664x; 1.2664x over previous
//
#include <hip/hip_runtime.h>

// B=4, N=4096, D=128 fixed by the reference setup.
// d_ws layout: [0, 4MiB) h as bf16 bits (ushort), [4MiB, +64KiB) sq fp32.

typedef float  f32x4   __attribute__((ext_vector_type(4)));
typedef float  f32x16  __attribute__((ext_vector_type(16)));
typedef short  bf16x8  __attribute__((ext_vector_type(8)));
typedef __attribute__((address_space(3))) void       lds_void_t;
typedef const __attribute__((address_space(1))) void gvoid_t;

__device__ inline float bf2f(unsigned int u) {
    union { unsigned int i; float f; } c; c.i = u << 16; return c.f;
}
__device__ inline unsigned short f2bf(float f) {
    union { float f; unsigned int i; } c; c.f = f;
    unsigned int r = c.i + 0x7fffu + ((c.i >> 16) & 1u);   // RNE
    return (unsigned short)(r >> 16);
}

// ---------------- Kernel A: h = bf16(x @ W^T + b), plus sq[row] = ||h_row||^2 ----
#define KA_ROWS 32
__global__ __launch_bounds__(256) void proj_kernel(
    const float* __restrict__ x, const float* __restrict__ W,
    const float* __restrict__ bias, unsigned short* __restrict__ h,
    float* __restrict__ sq)
{
    __shared__ __align__(16) unsigned short W5[32 * 4 * 32 * 4]; // 32 KiB
    __shared__ float xs[KA_ROWS][132];
    const int t = threadIdx.x;
    const long r0 = (long)blockIdx.x * KA_ROWS;

    for (int q = t; q < 4096; q += 256) {
        float4 w4 = ((const float4*)W)[q];
        int e = q >> 5, d4 = q & 31;
        int eb = e >> 2, ei = e & 3;
        ushort4 o;
        o.x = f2bf(w4.x); o.y = f2bf(w4.y); o.z = f2bf(w4.z); o.w = f2bf(w4.w);
        *(ushort4*)&W5[d4 * 256 + ei * 64 + ((eb ^ d4) & 31) * 4] = o;
    }
    const float4* xsrc = (const float4*)(x + r0 * 128);
    for (int q = t; q < KA_ROWS * 32; q += 256) {
        float4 v = xsrc[q];
        int r = q >> 5, d = (q & 31) << 2;
        xs[r][d] = v.x; xs[r][d + 1] = v.y; xs[r][d + 2] = v.z; xs[r][d + 3] = v.w;
    }
    __syncthreads();

    const int eb = t & 31, rb = t >> 5;
    const int e0 = eb * 4, rr0 = rb * 4;

    float acc_[4][4];
    #pragma unroll
    for (int ei = 0; ei < 4; ++ei) {
        float bv = bias[e0 + ei];
        #pragma unroll
        for (int ri = 0; ri < 4; ++ri) acc_[ri][ei] = bv;
    }

    for (int d4 = 0; d4 < 32; ++d4) {
        float wv[4][4];
        #pragma unroll
        for (int ei = 0; ei < 4; ++ei) {
            ushort4 u = *(const ushort4*)&W5[d4 * 256 + ei * 64 + ((eb ^ d4) & 31) * 4];
            wv[ei][0] = bf2f(u.x); wv[ei][1] = bf2f(u.y);
            wv[ei][2] = bf2f(u.z); wv[ei][3] = bf2f(u.w);
        }
        #pragma unroll
        for (int ri = 0; ri < 4; ++ri) {
            float4 xv = *(const float4*)&xs[rr0 + ri][d4 * 4];
            #pragma unroll
            for (int ei = 0; ei < 4; ++ei) {
                acc_[ri][ei] = fmaf(xv.x, wv[ei][0],
                               fmaf(xv.y, wv[ei][1],
                               fmaf(xv.z, wv[ei][2],
                               fmaf(xv.w, wv[ei][3], acc_[ri][ei]))));
            }
        }
    }

    float s[4] = {0.f, 0.f, 0.f, 0.f};
    #pragma unroll
    for (int ri = 0; ri < 4; ++ri) {
        ushort4 o;
        float v0 = bf2f(o.x = f2bf(acc_[ri][0]));
        float v1 = bf2f(o.y = f2bf(acc_[ri][1]));
        float v2 = bf2f(o.z = f2bf(acc_[ri][2]));
        float v3 = bf2f(o.w = f2bf(acc_[ri][3]));
        s[ri] = v0 * v0 + v1 * v1 + v2 * v2 + v3 * v3;
        *(ushort4*)&h[(r0 + rr0 + ri) * 128 + e0] = o;
    }
    #pragma unroll
    for (int ri = 0; ri < 4; ++ri) {
        #pragma unroll
        for (int m = 16; m > 0; m >>= 1) s[ri] += __shfl_xor(s[ri], m, 64);
    }
    if (eb == 0) {
        #pragma unroll
        for (int ri = 0; ri < 4; ++ri) sq[r0 + rr0 + ri] = s[ri];
    }
}

// ---------------- Kernel B: R15 champion widened to 1024 threads ---------------
// Same 256x256 tile, same panels/swizzle/XCD-affinity, same vmcnt-clean
// epilogue (sq in LDS; zero global loads after prologue). 16 waves in a 4x4
// grid of 64x64 quadrants -> 64 nt stores/thread (~VMEM queue depth): a wave
// issues its whole burst and hits s_endpgm fire-and-forget; the drain rides
// under the next block's stage+compute (block-level pipelining, the only
// overlap mechanism that has worked). 4 waves/SIMD also hides trans latency.
__global__ __launch_bounds__(1024, 4) void gram_kernel(
    const unsigned short* __restrict__ h, const float* __restrict__ sq,
    float* __restrict__ out)
{
    __shared__ __align__(16) unsigned short hsI[256 * 128];   // 64 KiB
    __shared__ __align__(16) unsigned short hsJ[256 * 128];   // 64 KiB
    __shared__ float sqs[512];                                // [0,256)=i, [256,512)=j
    const int bid = blockIdx.x;                       // 1024 blocks
    const int xcd = bid & 7;
    const int bb  = xcd >> 1;                         // batch -> XCD pair
    const int tloc = ((bid >> 3) << 1) | (xcd & 1);   // 0..255 tile in batch
    const int it = tloc >> 4, jt = tloc & 15;
    const int i0 = bb * 4096 + it * 256;
    const int j0 = bb * 4096 + jt * 256;
    const int t = threadIdx.x, w = t >> 6, lane = t & 63;

    const char* hb = (const char*)h;
    #pragma unroll
    for (int q = 0; q < 4; ++q) {
        int p   = (q * 1024 + t) << 4;                // linear byte off in panel
        int row = p >> 8;                             // 256 B per row
        int c   = (p >> 4) & 15;
        int cs  = c ^ (row & 15);                     // inverse swizzle at source
        __builtin_amdgcn_global_load_lds(
            (gvoid_t*)(hb + ((long)(i0 + row) << 8) + (cs << 4)),
            (lds_void_t*)(((char*)hsI) + (unsigned)p), 16, 0, 0);
        __builtin_amdgcn_global_load_lds(
            (gvoid_t*)(hb + ((long)(j0 + row) << 8) + (cs << 4)),
            (lds_void_t*)(((char*)hsJ) + (unsigned)p), 16, 0, 0);
    }
    // sq panels -> LDS (the ONLY global sq loads in the kernel)
    if (t < 512) sqs[t] = sq[((t >> 8) ? j0 : i0) + (t & 255)];
    __syncthreads();

    const int wr = w >> 2, wc = w & 3;      // 4x4 wave grid of 64x64 quadrants
    const int l31 = lane & 31, lh = lane >> 5;
    f32x16 acc[2][2] = {};
    const char* hI = (const char*)hsI;
    const char* hJ = (const char*)hsJ;

    #pragma unroll
    for (int ks = 0; ks < 8; ++ks) {        // K = 8 x 16
        bf16x8 af[2], bg[2];
        #pragma unroll
        for (int rb = 0; rb < 2; ++rb) {
            int rowA = wr * 64 + rb * 32 + l31;
            int cA = ((ks * 2 + lh) ^ (rowA & 15)) << 4;
            af[rb] = *(const bf16x8*)(hI + (rowA << 8) + cA);
            int rowB = wc * 64 + rb * 32 + l31;
            int cB = ((ks * 2 + lh) ^ (rowB & 15)) << 4;
            bg[rb] = *(const bf16x8*)(hJ + (rowB << 8) + cB);
        }
        #pragma unroll
        for (int rb = 0; rb < 2; ++rb)
            #pragma unroll
            for (int nb = 0; nb < 2; ++nb)
                acc[rb][nb] = __builtin_amdgcn_mfma_f32_32x32x16_bf16(
                    af[rb], bg[nb], acc[rb][nb], 0, 0, 0);
    }

    // epilogue: ZERO global loads (sq via ds_read -> lgkmcnt, not vmcnt)
    float sqj_r[2];
    #pragma unroll
    for (int nb = 0; nb < 2; ++nb) sqj_r[nb] = sqs[256 + wc * 64 + nb * 32 + l31];

    #pragma unroll
    for (int rb = 0; rb < 2; ++rb) {
        #pragma unroll
        for (int reg = 0; reg < 16; ++reg) {
            int il = wr * 64 + rb * 32 + (reg & 3) + 8 * (reg >> 2) + 4 * lh;
            float sqi_v = sqs[il];                    // LDS broadcast
            #pragma unroll
            for (int nb = 0; nb < 2; ++nb) {
                int jl = wc * 64 + nb * 32 + l31;
                float d2 = fmaxf(fmaf(acc[rb][nb][reg], -2.0f, sqi_v + sqj_r[nb]), 0.0f);
                float val = __expf(-__builtin_amdgcn_sqrtf(d2));
                if (it == jt && il == jl) val = 1.0f;     // exact diagonal
                __builtin_nontemporal_store(
                    val, &out[((long)(i0 + il) << 12) + (jt << 8) + jl]);
            }
        }
    }
}

extern "C" void kernel_launch(void* const* d_in, const int* in_sizes, int n_in,
                              void* d_out, int out_size, void* d_ws, size_t ws_size,
                              hipStream_t stream) {
    const float* x = (const float*)d_in[0];   // [4,4096,128]
    const float* W = (const float*)d_in[1];   // [128,128]
    const float* b = (const float*)d_in[2];   // [128]
    float* out = (float*)d_out;               // [4,4096,4096]

    unsigned short* h = (unsigned short*)d_ws;                       // 16384*128 bf16
    float* sq = (float*)((char*)d_ws + (size_t)16384 * 128 * 2);     // 16384 fp32

    proj_kernel<<<dim3(16384 / KA_ROWS), dim3(256), 0, stream>>>(x, W, b, h, sq);
    gram_kernel<<<dim3(1024), dim3(1024), 0, stream>>>(h, sq, out);
}

// Round 18
// 72.076 us; speedup vs baseline: 1.2961x; 1.0235x over previous
//
#include <hip/hip_runtime.h>

// B=4, N=4096, D=128 fixed by the reference setup.
// d_ws layout: [0, 4MiB) h as bf16 bits (ushort), [4MiB, +64KiB) sq fp32.

typedef float  f32x4   __attribute__((ext_vector_type(4)));
typedef float  f32x16  __attribute__((ext_vector_type(16)));
typedef short  bf16x8  __attribute__((ext_vector_type(8)));

__device__ inline float bf2f(unsigned int u) {
    union { unsigned int i; float f; } c; c.i = u << 16; return c.f;
}
__device__ inline unsigned short f2bf(float f) {
    union { float f; unsigned int i; } c; c.f = f;
    unsigned int r = c.i + 0x7fffu + ((c.i >> 16) & 1u);   // RNE
    return (unsigned short)(r >> 16);
}

// ---------------- Kernel A: h = bf16(x @ W^T + b), plus sq[row] = ||h_row||^2 ----
#define KA_ROWS 32
__global__ __launch_bounds__(256) void proj_kernel(
    const float* __restrict__ x, const float* __restrict__ W,
    const float* __restrict__ bias, unsigned short* __restrict__ h,
    float* __restrict__ sq)
{
    __shared__ __align__(16) unsigned short W5[32 * 4 * 32 * 4]; // 32 KiB
    __shared__ float xs[KA_ROWS][132];
    const int t = threadIdx.x;
    const long r0 = (long)blockIdx.x * KA_ROWS;

    for (int q = t; q < 4096; q += 256) {
        float4 w4 = ((const float4*)W)[q];
        int e = q >> 5, d4 = q & 31;
        int eb = e >> 2, ei = e & 3;
        ushort4 o;
        o.x = f2bf(w4.x); o.y = f2bf(w4.y); o.z = f2bf(w4.z); o.w = f2bf(w4.w);
        *(ushort4*)&W5[d4 * 256 + ei * 64 + ((eb ^ d4) & 31) * 4] = o;
    }
    const float4* xsrc = (const float4*)(x + r0 * 128);
    for (int q = t; q < KA_ROWS * 32; q += 256) {
        float4 v = xsrc[q];
        int r = q >> 5, d = (q & 31) << 2;
        xs[r][d] = v.x; xs[r][d + 1] = v.y; xs[r][d + 2] = v.z; xs[r][d + 3] = v.w;
    }
    __syncthreads();

    const int eb = t & 31, rb = t >> 5;
    const int e0 = eb * 4, rr0 = rb * 4;

    float acc_[4][4];
    #pragma unroll
    for (int ei = 0; ei < 4; ++ei) {
        float bv = bias[e0 + ei];
        #pragma unroll
        for (int ri = 0; ri < 4; ++ri) acc_[ri][ei] = bv;
    }

    for (int d4 = 0; d4 < 32; ++d4) {
        float wv[4][4];
        #pragma unroll
        for (int ei = 0; ei < 4; ++ei) {
            ushort4 u = *(const ushort4*)&W5[d4 * 256 + ei * 64 + ((eb ^ d4) & 31) * 4];
            wv[ei][0] = bf2f(u.x); wv[ei][1] = bf2f(u.y);
            wv[ei][2] = bf2f(u.z); wv[ei][3] = bf2f(u.w);
        }
        #pragma unroll
        for (int ri = 0; ri < 4; ++ri) {
            float4 xv = *(const float4*)&xs[rr0 + ri][d4 * 4];
            #pragma unroll
            for (int ei = 0; ei < 4; ++ei) {
                acc_[ri][ei] = fmaf(xv.x, wv[ei][0],
                               fmaf(xv.y, wv[ei][1],
                               fmaf(xv.z, wv[ei][2],
                               fmaf(xv.w, wv[ei][3], acc_[ri][ei]))));
            }
        }
    }

    float s[4] = {0.f, 0.f, 0.f, 0.f};
    #pragma unroll
    for (int ri = 0; ri < 4; ++ri) {
        ushort4 o;
        float v0 = bf2f(o.x = f2bf(acc_[ri][0]));
        float v1 = bf2f(o.y = f2bf(acc_[ri][1]));
        float v2 = bf2f(o.z = f2bf(acc_[ri][2]));
        float v3 = bf2f(o.w = f2bf(acc_[ri][3]));
        s[ri] = v0 * v0 + v1 * v1 + v2 * v2 + v3 * v3;
        *(ushort4*)&h[(r0 + rr0 + ri) * 128 + e0] = o;
    }
    #pragma unroll
    for (int ri = 0; ri < 4; ++ri) {
        #pragma unroll
        for (int m = 16; m > 0; m >>= 1) s[ri] += __shfl_xor(s[ri], m, 64);
    }
    if (eb == 0) {
        #pragma unroll
        for (int ri = 0; ri < 4; ++ri) sq[r0 + rr0 + ri] = s[ri];
    }
}

// ---------------- Kernel B: R15 champion with L2-hitting reg-staged prologue ---
// Identical to the 72.5 µs champion EXCEPT staging: coalesced global dwordx4
// loads -> VGPRs -> swizzled ds_write_b128 (replacing global_load_lds, which
// per R7-vs-R11 FETCH_SIZE evidence bypasses L2 and always fetches HBM).
// Resulting LDS layout is bit-identical (LDS[row][c] = global[row][c^(row&15)]),
// so K-loop and epilogue are untouched. HBM fetch should collapse 134->~8 MB.
__global__ __launch_bounds__(512, 2) void gram_kernel(
    const unsigned short* __restrict__ h, const float* __restrict__ sq,
    float* __restrict__ out)
{
    __shared__ __align__(16) unsigned short hsI[256 * 128];   // 64 KiB
    __shared__ __align__(16) unsigned short hsJ[256 * 128];   // 64 KiB
    __shared__ float sqs[512];                                // [0,256)=i, [256,512)=j
    const int bid = blockIdx.x;                       // 1024 blocks
    const int xcd = bid & 7;
    const int bb  = xcd >> 1;                         // batch -> XCD pair
    const int tloc = ((bid >> 3) << 1) | (xcd & 1);   // 0..255 tile in batch
    const int it = tloc >> 4, jt = tloc & 15;
    const int i0 = bb * 4096 + it * 256;
    const int j0 = bb * 4096 + jt * 256;
    const int t = threadIdx.x, w = t >> 6, lane = t & 63;

    const char* hb = (const char*)h;
    // ---- reg-staged, L2-allocating panel loads (coalesced 1 KB/wave-instr) ----
    f32x4 tI[8], tJ[8];
    #pragma unroll
    for (int q = 0; q < 8; ++q) {
        int p   = (q * 512 + t) << 4;                 // linear byte off in panel
        int row = p >> 8;                             // 256 B per row
        tI[q] = *(const f32x4*)(hb + ((long)(i0 + row) << 8) + (p & 255));
        tJ[q] = *(const f32x4*)(hb + ((long)(j0 + row) << 8) + (p & 255));
    }
    // sq panels -> LDS (the ONLY global sq loads in the kernel)
    sqs[t] = sq[((t >> 8) ? j0 : i0) + (t & 255)];
    #pragma unroll
    for (int q = 0; q < 8; ++q) {
        int p   = (q * 512 + t) << 4;
        int row = p >> 8;
        int c   = (p >> 4) & 15;
        int cs  = c ^ (row & 15);                     // swizzle at the WRITE
        *(f32x4*)(((char*)hsI) + row * 256 + (cs << 4)) = tI[q];
        *(f32x4*)(((char*)hsJ) + row * 256 + (cs << 4)) = tJ[q];
    }
    __syncthreads();

    const int wr = w >> 2, wc = w & 3;      // wave -> 128x64 quadrant
    const int l31 = lane & 31, lh = lane >> 5;
    f32x16 acc[4][2] = {};
    const char* hI = (const char*)hsI;
    const char* hJ = (const char*)hsJ;

    #pragma unroll
    for (int ks = 0; ks < 8; ++ks) {        // K = 8 x 16
        bf16x8 af[4], bg[2];
        #pragma unroll
        for (int rb = 0; rb < 4; ++rb) {
            int rowA = wr * 128 + rb * 32 + l31;
            int cA = ((ks * 2 + lh) ^ (rowA & 15)) << 4;
            af[rb] = *(const bf16x8*)(hI + (rowA << 8) + cA);
        }
        #pragma unroll
        for (int nb = 0; nb < 2; ++nb) {
            int rowB = wc * 64 + nb * 32 + l31;
            int cB = ((ks * 2 + lh) ^ (rowB & 15)) << 4;
            bg[nb] = *(const bf16x8*)(hJ + (rowB << 8) + cB);
        }
        #pragma unroll
        for (int rb = 0; rb < 4; ++rb)
            #pragma unroll
            for (int nb = 0; nb < 2; ++nb)
                acc[rb][nb] = __builtin_amdgcn_mfma_f32_32x32x16_bf16(
                    af[rb], bg[nb], acc[rb][nb], 0, 0, 0);
    }

    // epilogue: ZERO global loads (sq from LDS; ds_read = lgkmcnt, not vmcnt)
    float sqj_r[2];
    #pragma unroll
    for (int nb = 0; nb < 2; ++nb) sqj_r[nb] = sqs[256 + wc * 64 + nb * 32 + l31];

    #pragma unroll
    for (int rb = 0; rb < 4; ++rb) {
        #pragma unroll
        for (int reg = 0; reg < 16; ++reg) {
            int il = wr * 128 + rb * 32 + (reg & 3) + 8 * (reg >> 2) + 4 * lh;
            float sqi_v = sqs[il];                    // LDS broadcast
            #pragma unroll
            for (int nb = 0; nb < 2; ++nb) {
                int jl = wc * 64 + nb * 32 + l31;
                float d2 = fmaxf(fmaf(acc[rb][nb][reg], -2.0f, sqi_v + sqj_r[nb]), 0.0f);
                float val = __expf(-__builtin_amdgcn_sqrtf(d2));
                if (it == jt && il == jl) val = 1.0f;     // exact diagonal
                __builtin_nontemporal_store(
                    val, &out[((long)(i0 + il) << 12) + (jt << 8) + jl]);
            }
        }
    }
}

extern "C" void kernel_launch(void* const* d_in, const int* in_sizes, int n_in,
                              void* d_out, int out_size, void* d_ws, size_t ws_size,
                              hipStream_t stream) {
    const float* x = (const float*)d_in[0];   // [4,4096,128]
    const float* W = (const float*)d_in[1];   // [128,128]
    const float* b = (const float*)d_in[2];   // [128]
    float* out = (float*)d_out;               // [4,4096,4096]

    unsigned short* h = (unsigned short*)d_ws;                       // 16384*128 bf16
    float* sq = (float*)((char*)d_ws + (size_t)16384 * 128 * 2);     // 16384 fp32

    proj_kernel<<<dim3(16384 / KA_ROWS), dim3(256), 0, stream>>>(x, W, b, h, sq);
    gram_kernel<<<dim3(1024), dim3(512), 0, stream>>>(h, sq, out);
}

// Round 19
// 68.658 us; speedup vs baseline: 1.3606x; 1.0498x over previous
//
#include <hip/hip_runtime.h>

// B=4, N=4096, D=128 fixed by the reference setup.
// d_ws layout: [0, 4MiB) h as bf16 bits (ushort), [4MiB, +64KiB) sq fp32.

typedef float  f32x4   __attribute__((ext_vector_type(4)));
typedef float  f32x16  __attribute__((ext_vector_type(16)));
typedef short  bf16x8  __attribute__((ext_vector_type(8)));

__device__ inline float bf2f(unsigned int u) {
    union { unsigned int i; float f; } c; c.i = u << 16; return c.f;
}
__device__ inline unsigned short f2bf(float f) {
    union { float f; unsigned int i; } c; c.f = f;
    unsigned int r = c.i + 0x7fffu + ((c.i >> 16) & 1u);   // RNE
    return (unsigned short)(r >> 16);
}

// ---------------- Kernel A: h = bf16(x @ W^T + b), plus sq[row] = ||h_row||^2 ----
#define KA_ROWS 32
__global__ __launch_bounds__(256) void proj_kernel(
    const float* __restrict__ x, const float* __restrict__ W,
    const float* __restrict__ bias, unsigned short* __restrict__ h,
    float* __restrict__ sq)
{
    __shared__ __align__(16) unsigned short W5[32 * 4 * 32 * 4]; // 32 KiB
    __shared__ float xs[KA_ROWS][132];
    const int t = threadIdx.x;
    const long r0 = (long)blockIdx.x * KA_ROWS;

    for (int q = t; q < 4096; q += 256) {
        float4 w4 = ((const float4*)W)[q];
        int e = q >> 5, d4 = q & 31;
        int eb = e >> 2, ei = e & 3;
        ushort4 o;
        o.x = f2bf(w4.x); o.y = f2bf(w4.y); o.z = f2bf(w4.z); o.w = f2bf(w4.w);
        *(ushort4*)&W5[d4 * 256 + ei * 64 + ((eb ^ d4) & 31) * 4] = o;
    }
    const float4* xsrc = (const float4*)(x + r0 * 128);
    for (int q = t; q < KA_ROWS * 32; q += 256) {
        float4 v = xsrc[q];
        int r = q >> 5, d = (q & 31) << 2;
        xs[r][d] = v.x; xs[r][d + 1] = v.y; xs[r][d + 2] = v.z; xs[r][d + 3] = v.w;
    }
    __syncthreads();

    const int eb = t & 31, rb = t >> 5;
    const int e0 = eb * 4, rr0 = rb * 4;

    float acc_[4][4];
    #pragma unroll
    for (int ei = 0; ei < 4; ++ei) {
        float bv = bias[e0 + ei];
        #pragma unroll
        for (int ri = 0; ri < 4; ++ri) acc_[ri][ei] = bv;
    }

    for (int d4 = 0; d4 < 32; ++d4) {
        float wv[4][4];
        #pragma unroll
        for (int ei = 0; ei < 4; ++ei) {
            ushort4 u = *(const ushort4*)&W5[d4 * 256 + ei * 64 + ((eb ^ d4) & 31) * 4];
            wv[ei][0] = bf2f(u.x); wv[ei][1] = bf2f(u.y);
            wv[ei][2] = bf2f(u.z); wv[ei][3] = bf2f(u.w);
        }
        #pragma unroll
        for (int ri = 0; ri < 4; ++ri) {
            float4 xv = *(const float4*)&xs[rr0 + ri][d4 * 4];
            #pragma unroll
            for (int ei = 0; ei < 4; ++ei) {
                acc_[ri][ei] = fmaf(xv.x, wv[ei][0],
                               fmaf(xv.y, wv[ei][1],
                               fmaf(xv.z, wv[ei][2],
                               fmaf(xv.w, wv[ei][3], acc_[ri][ei]))));
            }
        }
    }

    float s[4] = {0.f, 0.f, 0.f, 0.f};
    #pragma unroll
    for (int ri = 0; ri < 4; ++ri) {
        ushort4 o;
        float v0 = bf2f(o.x = f2bf(acc_[ri][0]));
        float v1 = bf2f(o.y = f2bf(acc_[ri][1]));
        float v2 = bf2f(o.z = f2bf(acc_[ri][2]));
        float v3 = bf2f(o.w = f2bf(acc_[ri][3]));
        s[ri] = v0 * v0 + v1 * v1 + v2 * v2 + v3 * v3;
        *(ushort4*)&h[(r0 + rr0 + ri) * 128 + e0] = o;
    }
    #pragma unroll
    for (int ri = 0; ri < 4; ++ri) {
        #pragma unroll
        for (int m = 16; m > 0; m >>= 1) s[ri] += __shfl_xor(s[ri], m, 64);
    }
    if (eb == 0) {
        #pragma unroll
        for (int ri = 0; ri < 4; ++ri) sq[r0 + rr0 + ri] = s[ri];
    }
}

// ---------------- Kernel B: 128x128 tile, 2 blocks/CU, vmcnt-clean epilogue ----
// Small-LDS variant of the champion: panels 2x32 KiB + sqs = 68 KiB -> TWO
// blocks co-resident per CU. While block A's 64 KB store burst drains, block
// B stages/computes on the same CU — the overlap the 1-block/CU champion
// never got (its 4x ~6 µs serial phases were fully exposed). Same proven
// pieces: reg-staged L2-allocating loads, XOR swizzle both-sides, XCD
// affinity, sq in LDS (zero global loads after prologue), nt dword stores.
__global__ __launch_bounds__(256, 2) void gram_kernel(
    const unsigned short* __restrict__ h, const float* __restrict__ sq,
    float* __restrict__ out)
{
    __shared__ __align__(16) unsigned short hsI[128 * 128];   // 32 KiB
    __shared__ __align__(16) unsigned short hsJ[128 * 128];   // 32 KiB
    __shared__ float sqs[256];                                // [0,128)=i, [128,256)=j
    const int bid = blockIdx.x;                       // 4096 blocks
    const int xcd = bid & 7;
    const int bb  = xcd >> 1;                         // batch -> XCD pair
    const int tloc = ((bid >> 3) << 1) | (xcd & 1);   // 0..1023 tile in batch
    const int it = tloc >> 5, jt = tloc & 31;
    const int i0 = bb * 4096 + it * 128;
    const int j0 = bb * 4096 + jt * 128;
    const int t = threadIdx.x, w = t >> 6, lane = t & 63;

    const char* hb = (const char*)h;
    // reg-staged, L2-allocating panel loads (coalesced 1 KB/wave-instr)
    f32x4 tI[8], tJ[8];
    #pragma unroll
    for (int q = 0; q < 8; ++q) {
        int p   = (q * 256 + t) << 4;                 // byte off in 32 KiB panel
        int row = p >> 8;                             // 256 B per row
        tI[q] = *(const f32x4*)(hb + ((long)(i0 + row) << 8) + (p & 255));
        tJ[q] = *(const f32x4*)(hb + ((long)(j0 + row) << 8) + (p & 255));
    }
    sqs[t] = sq[((t >> 7) ? j0 - 128 : i0) + t];      // t<128: i, t>=128: j
    #pragma unroll
    for (int q = 0; q < 8; ++q) {
        int p   = (q * 256 + t) << 4;
        int row = p >> 8;
        int c   = (p >> 4) & 15;
        int cs  = c ^ (row & 15);                     // swizzle at the WRITE
        *(f32x4*)(((char*)hsI) + row * 256 + (cs << 4)) = tI[q];
        *(f32x4*)(((char*)hsJ) + row * 256 + (cs << 4)) = tJ[q];
    }
    __syncthreads();

    const int wr = w >> 1, wc = w & 1;      // wave -> 64x64 quadrant
    const int l31 = lane & 31, lh = lane >> 5;
    f32x16 acc[2][2] = {};
    const char* hI = (const char*)hsI;
    const char* hJ = (const char*)hsJ;

    #pragma unroll
    for (int ks = 0; ks < 8; ++ks) {        // K = 8 x 16
        bf16x8 af[2], bg[2];
        #pragma unroll
        for (int rb = 0; rb < 2; ++rb) {
            int rowA = wr * 64 + rb * 32 + l31;
            int cA = ((ks * 2 + lh) ^ (rowA & 15)) << 4;
            af[rb] = *(const bf16x8*)(hI + (rowA << 8) + cA);
            int rowB = wc * 64 + rb * 32 + l31;
            int cB = ((ks * 2 + lh) ^ (rowB & 15)) << 4;
            bg[rb] = *(const bf16x8*)(hJ + (rowB << 8) + cB);
        }
        #pragma unroll
        for (int rb = 0; rb < 2; ++rb)
            #pragma unroll
            for (int nb = 0; nb < 2; ++nb)
                acc[rb][nb] = __builtin_amdgcn_mfma_f32_32x32x16_bf16(
                    af[rb], bg[nb], acc[rb][nb], 0, 0, 0);
    }

    // epilogue: ZERO global loads (sq via ds_read -> lgkmcnt, not vmcnt)
    float sqj_r[2];
    #pragma unroll
    for (int nb = 0; nb < 2; ++nb) sqj_r[nb] = sqs[128 + wc * 64 + nb * 32 + l31];

    #pragma unroll
    for (int rb = 0; rb < 2; ++rb) {
        #pragma unroll
        for (int reg = 0; reg < 16; ++reg) {
            int il = wr * 64 + rb * 32 + (reg & 3) + 8 * (reg >> 2) + 4 * lh;
            float sqi_v = sqs[il];                    // LDS broadcast
            #pragma unroll
            for (int nb = 0; nb < 2; ++nb) {
                int jl = wc * 64 + nb * 32 + l31;
                float d2 = fmaxf(fmaf(acc[rb][nb][reg], -2.0f, sqi_v + sqj_r[nb]), 0.0f);
                float val = __expf(-__builtin_amdgcn_sqrtf(d2));
                if (it == jt && il == jl) val = 1.0f;     // exact diagonal
                __builtin_nontemporal_store(
                    val, &out[((long)(i0 + il) << 12) + (jt << 7) + jl]);
            }
        }
    }
}

extern "C" void kernel_launch(void* const* d_in, const int* in_sizes, int n_in,
                              void* d_out, int out_size, void* d_ws, size_t ws_size,
                              hipStream_t stream) {
    const float* x = (const float*)d_in[0];   // [4,4096,128]
    const float* W = (const float*)d_in[1];   // [128,128]
    const float* b = (const float*)d_in[2];   // [128]
    float* out = (float*)d_out;               // [4,4096,4096]

    unsigned short* h = (unsigned short*)d_ws;                       // 16384*128 bf16
    float* sq = (float*)((char*)d_ws + (size_t)16384 * 128 * 2);     // 16384 fp32

    proj_kernel<<<dim3(16384 / KA_ROWS), dim3(256), 0, stream>>>(x, W, b, h, sq);
    gram_kernel<<<dim3(4096), dim3(256), 0, stream>>>(h, sq, out);
}